// Round 2
// baseline (639.322 us; speedup 1.0000x reference)
//
#include <hip/hip_runtime.h>

// Problem constants: bs=16384, C=10000, M=6, D=256
constexpr int kBS = 16384;
constexpr int kC  = 10000;
constexpr int kM  = 6;
constexpr int kD  = 256;
constexpr float kEPS = 1e-4f;
constexpr int kNPart = 256;   // loss partial slots (== blockDim of k_agg)

// ---------- Kernel 1: per-row weights + sum_v + linked lists ---------------
// One thread per row. Computes the label-MLP head (h, sigmoid, cumsum) and
// the per-row normalized weights nw[6] ONCE, so k_agg has zero
// transcendentals. Also builds the per-label linked list and zeroes the
// loss partials + done counter (block 0).
__global__ __launch_bounds__(256) void k_build(
    const int*   __restrict__ labels,   // [BS]
    const float* __restrict__ beta,     // [BS]
    const float* __restrict__ W1,       // [M, C]
    const float* __restrict__ b1,       // [M]
    const float* __restrict__ W2,       // [M, M]
    const float* __restrict__ b2,       // [M]
    int*         head,                  // ws: [C], pre-set to -1 (memset 0xFF)
    int*   __restrict__ next,           // ws: [BS]
    float* __restrict__ nwbuf,          // ws: [BS, 8] normalized weights (pad 8)
    float* __restrict__ partial,        // ws: [kNPart]
    int*   __restrict__ counter,        // ws: [1]
    float* __restrict__ sum_v)          // out: [BS, M]
{
    const int row = blockIdx.x * 256 + threadIdx.x;

    // zero loss partials + done counter (ws is dirty between iterations)
    if (blockIdx.x == 0) {
        if (threadIdx.x < kNPart) partial[threadIdx.x] = 0.f;
        if (threadIdx.x == 0)     *counter = 0;
    }
    if (row >= kBS) return;

    const int lab = labels[row];
    next[row] = atomicExch(head + lab, row);

    // --- MLP head (label-dependent) ---
    float h[kM];
#pragma unroll
    for (int m = 0; m < kM; ++m) {
        const float v = W1[m * kC + lab] + b1[m];
        h[m] = v > 0.f ? v : 0.f;
    }
    float csm[kM];
    float cs = 0.f;
#pragma unroll
    for (int m = 0; m < kM; ++m) {
        float z = b2[m];
#pragma unroll
        for (int j = 0; j < kM; ++j) z += W2[m * kM + j] * h[j];
        cs += 1.f / (1.f + expf(-z)) + kEPS;
        csm[m] = cs;
    }

    // --- per-row normalized weights ---
    const float br = beta[row];
    float nw[kM];
    float wsum = 0.f;
#pragma unroll
    for (int m = 0; m < kM; ++m) {
        const float d = br - csm[m];
        const float w = expf(-sqrtf(d * d + 1e-10f));
        nw[m] = w;
        wsum += w;
    }
    const float inv = 1.f / (wsum + kEPS + 1e-10f);

    // store normalized weights, padded to 8 floats (32B) for aligned loads
    float4 lo = make_float4(nw[0] * inv, nw[1] * inv, nw[2] * inv, nw[3] * inv);
    float2 hi = make_float2(nw[4] * inv, nw[5] * inv);
    ((float4*)(nwbuf + (size_t)row * 8))[0]     = lo;
    ((float2*)(nwbuf + (size_t)row * 8 + 4))[0] = hi;

    // sum_v output (contiguous 24B per thread, coalesced across the block)
#pragma unroll
    for (int m = 0; m < kM; ++m) sum_v[row * kM + m] = csm[m];
}

// ---------- Kernel 2: aggregation — one block per label, pure FMA ----------
// 256 threads; thread owns element d = threadIdx.x of every M-row.
// Chase is block-uniform (scalar loads); weights come precomputed from ws.
// Last finishing block reduces the loss partials (3rd dispatch eliminated).
__global__ __launch_bounds__(256) void k_agg(
    const float* __restrict__ data,     // [BS, D]
    const int*   __restrict__ head,     // ws: [C]
    const int*   __restrict__ next,     // ws: [BS]
    const float* __restrict__ nwbuf,    // ws: [BS, 8]
    const float* __restrict__ centers,  // [C*M, D]
    const float* __restrict__ memory,   // [C*M, D]
    const float* __restrict__ memw,     // [C*M]
    float*       partial,               // ws: [kNPart]
    int*         counter,               // ws: [1]
    float* __restrict__ loss_out,       // out: [1]
    float* __restrict__ mem_out,        // out: [C*M, D]
    float* __restrict__ mw_out)         // out: [C*M]
{
    __shared__ float ls[4];
    __shared__ int   sdone;
    const int lab  = blockIdx.x;
    const int tid  = threadIdx.x;
    const int lane = tid & 63;
    const int wid  = tid >> 6;
    const size_t cbase = (size_t)lab * (kM * kD) + tid;

    // prefetch this label's centers & memory elements (independent loads)
    float cv[kM], mv[kM];
#pragma unroll
    for (int m = 0; m < kM; ++m) {
        cv[m] = centers[cbase + (size_t)m * kD];
        mv[m] = memory [cbase + (size_t)m * kD];
    }

    float acc[kM], mwacc[kM];
#pragma unroll
    for (int m = 0; m < kM; ++m) { acc[m] = 0.f; mwacc[m] = 0.f; }
    float lossacc = 0.f;

    int row = head[lab];
    while (row >= 0) {
        // collect up to 4 row ids (block-uniform chase over L2-hot next[])
        int rows[4];
        int cnt = 0;
        while (row >= 0 && cnt < 4) { rows[cnt++] = row; row = next[row]; }

        // batch-issue all payload loads (independent -> vmcnt pipelines)
        float  dv[4];
        float4 wlo[4];
        float2 whi[4];
#pragma unroll
        for (int i = 0; i < 4; ++i) if (i < cnt) {
            dv[i]  = data[(size_t)rows[i] * kD + tid];
            wlo[i] = ((const float4*)(nwbuf + (size_t)rows[i] * 8))[0];
            whi[i] = ((const float2*)(nwbuf + (size_t)rows[i] * 8 + 4))[0];
        }

#pragma unroll
        for (int i = 0; i < 4; ++i) if (i < cnt) {
            float nw[kM] = { wlo[i].x, wlo[i].y, wlo[i].z, wlo[i].w,
                             whi[i].x, whi[i].y };
            float cm = 0.f;
#pragma unroll
            for (int m = 0; m < kM; ++m) {
                cm       += nw[m] * cv[m];
                acc[m]   += nw[m] * dv[i];
                mwacc[m] += nw[m];
            }
            const float ax = dv[i] - cm;
            lossacc += ax * ax;
        }
    }

    // mem_out = memory + acc (full coverage: every label, every element)
#pragma unroll
    for (int m = 0; m < kM; ++m)
        mem_out[cbase + (size_t)m * kD] = mv[m] + acc[m];

    // mw_out (threads 0..5; mwacc is block-uniform)
    float msel = mwacc[0];
    msel = (tid == 1) ? mwacc[1] : msel;
    msel = (tid == 2) ? mwacc[2] : msel;
    msel = (tid == 3) ? mwacc[3] : msel;
    msel = (tid == 4) ? mwacc[4] : msel;
    msel = (tid == 5) ? mwacc[5] : msel;
    if (tid < kM) {
        const size_t i = (size_t)lab * kM + tid;
        mw_out[i] = memw[i] + msel;
    }

    // ---- loss: block reduce -> low-contention partial atomic ----
#pragma unroll
    for (int off = 32; off > 0; off >>= 1) lossacc += __shfl_down(lossacc, off, 64);
    if (lane == 0) ls[wid] = lossacc;
    __syncthreads();
    if (tid == 0) {
        const float sb = ls[0] + ls[1] + ls[2] + ls[3];
        atomicAdd(partial + (lab & (kNPart - 1)), sb);
        __threadfence();                       // partial visible before counter
        const int old = atomicAdd(counter, 1);
        sdone = (old == (int)gridDim.x - 1) ? 1 : 0;
    }
    __syncthreads();

    // ---- last block folds partials into the scalar loss ----
    if (sdone) {
        // atomic read (device scope) avoids stale per-XCD cache lines
        float s = atomicAdd(partial + tid, 0.f);
#pragma unroll
        for (int off = 32; off > 0; off >>= 1) s += __shfl_down(s, off, 64);
        if (lane == 0) ls[wid] = s;
        __syncthreads();
        if (tid == 0)
            *loss_out = (ls[0] + ls[1] + ls[2] + ls[3]) *
                        (1.f / ((float)kBS * (float)kD));
    }
}

extern "C" void kernel_launch(void* const* d_in, const int* in_sizes, int n_in,
                              void* d_out, int out_size, void* d_ws, size_t ws_size,
                              hipStream_t stream) {
    const float* data    = (const float*)d_in[0];
    const int*   labels  = (const int*)  d_in[1];
    const float* beta    = (const float*)d_in[2];
    const float* centers = (const float*)d_in[3];
    const float* W1      = (const float*)d_in[4];
    const float* b1      = (const float*)d_in[5];
    const float* W2      = (const float*)d_in[6];
    const float* b2      = (const float*)d_in[7];
    const float* memory  = (const float*)d_in[8];
    const float* memw    = (const float*)d_in[9];

    float* out     = (float*)d_out;
    float* loss    = out;                                   // [1]
    float* sum_v   = out + 1;                               // [BS*M]
    float* mem_out = out + 1 + (size_t)kBS * kM;            // [C*M*D]
    float* mw_out  = mem_out + (size_t)kC * kM * kD;        // [C*M]

    // workspace layout: head[C] | next[BS] | partial[kNPart] | counter[1] | nwbuf[BS*8]
    int*   head    = (int*)d_ws;
    int*   next    = head + kC;
    float* partial = (float*)(next + kBS);
    int*   counter = (int*)(partial + kNPart);
    float* nwbuf   = (float*)(counter + 1);

    hipMemsetAsync(head, 0xFF, kC * sizeof(int), stream);   // head[i] = -1

    k_build<<<dim3(kBS / 256), dim3(256), 0, stream>>>(
        labels, beta, W1, b1, W2, b2, head, next, nwbuf, partial, counter, sum_v);

    k_agg<<<dim3(kC), dim3(256), 0, stream>>>(
        data, head, next, nwbuf, centers, memory, memw,
        partial, counter, loss, sum_v ? mem_out : mem_out, mw_out);
}

// Round 3
// 199.449 us; speedup vs baseline: 3.2054x; 3.2054x over previous
//
#include <hip/hip_runtime.h>

// Problem constants: bs=16384, C=10000, M=6, D=256
constexpr int kBS = 16384;
constexpr int kC  = 10000;
constexpr int kM  = 6;
constexpr int kD  = 256;
constexpr float kEPS = 1e-4f;
constexpr int kNPart = 256;   // loss partial slots (low-contention atomics)

// ---------- Kernel 1: per-row weights + sum_v + linked lists ---------------
// One thread per row. Computes the label-MLP head (h, sigmoid, cumsum) and
// the per-row normalized weights nw[6] ONCE, so k_agg has zero
// transcendentals. Also builds the per-label linked list and zeroes the
// loss partials (block 0).
__global__ __launch_bounds__(256) void k_build(
    const int*   __restrict__ labels,   // [BS]
    const float* __restrict__ beta,     // [BS]
    const float* __restrict__ W1,       // [M, C]
    const float* __restrict__ b1,       // [M]
    const float* __restrict__ W2,       // [M, M]
    const float* __restrict__ b2,       // [M]
    int*         head,                  // ws: [C], pre-set to -1 (memset 0xFF)
    int*   __restrict__ next,           // ws: [BS]
    float* __restrict__ nwbuf,          // ws: [BS, 8] normalized weights (pad 8)
    float* __restrict__ partial,        // ws: [kNPart]
    float* __restrict__ sum_v)          // out: [BS, M]
{
    const int row = blockIdx.x * 256 + threadIdx.x;

    // zero loss partials (ws is dirty between iterations)
    if (blockIdx.x == 0 && threadIdx.x < kNPart) partial[threadIdx.x] = 0.f;
    if (row >= kBS) return;

    const int lab = labels[row];
    next[row] = atomicExch(head + lab, row);

    // --- MLP head (label-dependent) ---
    float h[kM];
#pragma unroll
    for (int m = 0; m < kM; ++m) {
        const float v = W1[m * kC + lab] + b1[m];
        h[m] = v > 0.f ? v : 0.f;
    }
    float csm[kM];
    float cs = 0.f;
#pragma unroll
    for (int m = 0; m < kM; ++m) {
        float z = b2[m];
#pragma unroll
        for (int j = 0; j < kM; ++j) z += W2[m * kM + j] * h[j];
        cs += 1.f / (1.f + expf(-z)) + kEPS;
        csm[m] = cs;
    }

    // --- per-row normalized weights ---
    const float br = beta[row];
    float nw[kM];
    float wsum = 0.f;
#pragma unroll
    for (int m = 0; m < kM; ++m) {
        const float d = br - csm[m];
        const float w = expf(-sqrtf(d * d + 1e-10f));
        nw[m] = w;
        wsum += w;
    }
    const float inv = 1.f / (wsum + kEPS + 1e-10f);

    // store normalized weights, padded to 8 floats (32B) for aligned loads
    float4 lo = make_float4(nw[0] * inv, nw[1] * inv, nw[2] * inv, nw[3] * inv);
    float2 hi = make_float2(nw[4] * inv, nw[5] * inv);
    ((float4*)(nwbuf + (size_t)row * 8))[0]     = lo;
    ((float2*)(nwbuf + (size_t)row * 8 + 4))[0] = hi;

    // sum_v output (contiguous 24B per thread)
#pragma unroll
    for (int m = 0; m < kM; ++m) sum_v[row * kM + m] = csm[m];
}

// ---------- Kernel 2: aggregation — one block per label, pure FMA ----------
// 256 threads; thread owns element d = threadIdx.x of every M-row.
// Chase is block-uniform (broadcast loads over L2-hot next[]); weights come
// precomputed from ws. NO device-scope fences in this kernel (round-2 lesson:
// a __threadfence per block collapsed HBM to 265 GB/s via L2 flushes).
__global__ __launch_bounds__(256) void k_agg(
    const float* __restrict__ data,     // [BS, D]
    const int*   __restrict__ head,     // ws: [C]
    const int*   __restrict__ next,     // ws: [BS]
    const float* __restrict__ nwbuf,    // ws: [BS, 8]
    const float* __restrict__ centers,  // [C*M, D]
    const float* __restrict__ memory,   // [C*M, D]
    const float* __restrict__ memw,     // [C*M]
    float*       partial,               // ws: [kNPart]
    float* __restrict__ mem_out,        // out: [C*M, D]
    float* __restrict__ mw_out)         // out: [C*M]
{
    __shared__ float ls[4];
    const int lab  = blockIdx.x;
    const int tid  = threadIdx.x;
    const int lane = tid & 63;
    const int wid  = tid >> 6;
    const size_t cbase = (size_t)lab * (kM * kD) + tid;

    // prefetch this label's centers & memory elements (independent loads)
    float cv[kM], mv[kM];
#pragma unroll
    for (int m = 0; m < kM; ++m) {
        cv[m] = centers[cbase + (size_t)m * kD];
        mv[m] = memory [cbase + (size_t)m * kD];
    }

    float acc[kM], mwacc[kM];
#pragma unroll
    for (int m = 0; m < kM; ++m) { acc[m] = 0.f; mwacc[m] = 0.f; }
    float lossacc = 0.f;

    int row = head[lab];
    while (row >= 0) {
        // collect up to 4 row ids (block-uniform chase over L2-hot next[])
        int rows[4];
        int cnt = 0;
        while (row >= 0 && cnt < 4) { rows[cnt++] = row; row = next[row]; }

        // batch-issue all payload loads (independent -> vmcnt pipelines)
        float  dv[4];
        float4 wlo[4];
        float2 whi[4];
#pragma unroll
        for (int i = 0; i < 4; ++i) if (i < cnt) {
            dv[i]  = data[(size_t)rows[i] * kD + tid];
            wlo[i] = ((const float4*)(nwbuf + (size_t)rows[i] * 8))[0];
            whi[i] = ((const float2*)(nwbuf + (size_t)rows[i] * 8 + 4))[0];
        }

#pragma unroll
        for (int i = 0; i < 4; ++i) if (i < cnt) {
            float nw[kM] = { wlo[i].x, wlo[i].y, wlo[i].z, wlo[i].w,
                             whi[i].x, whi[i].y };
            float cm = 0.f;
#pragma unroll
            for (int m = 0; m < kM; ++m) {
                cm       += nw[m] * cv[m];
                acc[m]   += nw[m] * dv[i];
                mwacc[m] += nw[m];
            }
            const float ax = dv[i] - cm;
            lossacc += ax * ax;
        }
    }

    // mem_out = memory + acc (full coverage: every label, every element)
#pragma unroll
    for (int m = 0; m < kM; ++m)
        mem_out[cbase + (size_t)m * kD] = mv[m] + acc[m];

    // mw_out (threads 0..5; mwacc is block-uniform)
    float msel = mwacc[0];
    msel = (tid == 1) ? mwacc[1] : msel;
    msel = (tid == 2) ? mwacc[2] : msel;
    msel = (tid == 3) ? mwacc[3] : msel;
    msel = (tid == 4) ? mwacc[4] : msel;
    msel = (tid == 5) ? mwacc[5] : msel;
    if (tid < kM) {
        const size_t i = (size_t)lab * kM + tid;
        mw_out[i] = memw[i] + msel;
    }

    // loss: block reduce -> one low-contention atomic per block
#pragma unroll
    for (int off = 32; off > 0; off >>= 1) lossacc += __shfl_down(lossacc, off, 64);
    if (lane == 0) ls[wid] = lossacc;
    __syncthreads();
    if (tid == 0)
        atomicAdd(partial + (lab & (kNPart - 1)), ls[0] + ls[1] + ls[2] + ls[3]);
}

// ---------- Kernel 3: final loss reduction (one wave, ~2 us) ---------------
__global__ __launch_bounds__(64) void k_loss(
    const float* __restrict__ partial,
    float* __restrict__ loss_out)
{
    float s = 0.f;
#pragma unroll
    for (int i = 0; i < kNPart / 64; ++i) s += partial[i * 64 + threadIdx.x];
#pragma unroll
    for (int off = 32; off > 0; off >>= 1) s += __shfl_down(s, off, 64);
    if (threadIdx.x == 0) *loss_out = s * (1.f / ((float)kBS * (float)kD));
}

extern "C" void kernel_launch(void* const* d_in, const int* in_sizes, int n_in,
                              void* d_out, int out_size, void* d_ws, size_t ws_size,
                              hipStream_t stream) {
    const float* data    = (const float*)d_in[0];
    const int*   labels  = (const int*)  d_in[1];
    const float* beta    = (const float*)d_in[2];
    const float* centers = (const float*)d_in[3];
    const float* W1      = (const float*)d_in[4];
    const float* b1      = (const float*)d_in[5];
    const float* W2      = (const float*)d_in[6];
    const float* b2      = (const float*)d_in[7];
    const float* memory  = (const float*)d_in[8];
    const float* memw    = (const float*)d_in[9];

    float* out     = (float*)d_out;
    float* loss    = out;                                   // [1]
    float* sum_v   = out + 1;                               // [BS*M]
    float* mem_out = out + 1 + (size_t)kBS * kM;            // [C*M*D]
    float* mw_out  = mem_out + (size_t)kC * kM * kD;        // [C*M]

    // workspace layout: head[C] | next[BS] | partial[kNPart] | nwbuf[BS*8]
    int*   head    = (int*)d_ws;
    int*   next    = head + kC;
    float* partial = (float*)(next + kBS);
    float* nwbuf   = partial + kNPart;

    hipMemsetAsync(head, 0xFF, kC * sizeof(int), stream);   // head[i] = -1

    k_build<<<dim3(kBS / 256), dim3(256), 0, stream>>>(
        labels, beta, W1, b1, W2, b2, head, next, nwbuf, partial, sum_v);

    k_agg<<<dim3(kC), dim3(256), 0, stream>>>(
        data, head, next, nwbuf, centers, memory, memw,
        partial, mem_out, mw_out);

    k_loss<<<dim3(1), dim3(64), 0, stream>>>(partial, loss);
}